// Round 3
// baseline (548.547 us; speedup 1.0000x reference)
//
#include <hip/hip_runtime.h>
#include <math.h>

#define NSUBJ 8192
#define NTT   512
#define OBS   9
#define LOG2PI 1.8378770664093453f

__global__ void zero_out_kernel(float* out) { out[0] = 0.0f; }

__device__ __forceinline__ float fast_rcp(float x) { return __builtin_amdgcn_rcpf(x); }

// Swap adjacent lanes (0<->1, 2<->3, ...) via DPP quad_perm [1,0,3,2] — pure
// VALU, no LDS round-trip (shfl_xor compiles to ds_bpermute, ~120cyc latency).
__device__ __forceinline__ float swap1(float x) {
    int r = __builtin_amdgcn_update_dpp(0, __float_as_int(x), 0xB1, 0xF, 0xF, true);
    return __int_as_float(r);
}

// ---------------------------------------------------------------------------
// Kernel 1: data-independent Riccati recursion, run once on 1 block.
// Lane parity = regime (unified formulation). Stores per (t, regime):
// Sinv (6 floats, = filtered covariance) + log-constant, padded to 8 floats.
// ---------------------------------------------------------------------------
__global__ __launch_bounds__(64, 1) void precomp_kernel(
    const float* __restrict__ b1_r1, const float* __restrict__ lam1f,
    const float* __restrict__ q1d,   const float* __restrict__ b2_in,
    const float* __restrict__ lam2f, const float* __restrict__ q2d,
    const float* __restrict__ r_in,  float* __restrict__ tab)
{
    const int lane = threadIdx.x;
    const bool is2 = (lane & 1) != 0;

    float Rinv[9];
    float logdetR = 0.0f;
    #pragma unroll
    for (int i = 0; i < 9; ++i) {
        float r = fabsf(r_in[i]) + 1e-4f;
        Rinv[i] = 1.0f / r;
        logdetR += __logf(r);
    }
    const float C0 = 9.0f * LOG2PI + logdetR;

    float Bm[9];
    {
        float a0 = b1_r1[0], a1 = b1_r1[1], a2 = b1_r1[2];
        Bm[0] = is2 ? b2_in[0] : a0;   Bm[1] = is2 ? b2_in[1] : 0.0f;
        Bm[2] = is2 ? b2_in[2] : 0.0f; Bm[3] = is2 ? b2_in[3] : 0.0f;
        Bm[4] = is2 ? b2_in[4] : a1;   Bm[5] = is2 ? b2_in[5] : 0.0f;
        Bm[6] = is2 ? b2_in[6] : 0.0f; Bm[7] = is2 ? b2_in[7] : 0.0f;
        Bm[8] = is2 ? b2_in[8] : a2;
    }
    float lam[9];
    lam[0] = 1.0f;
    lam[1] = is2 ? lam2f[0] : lam1f[0];
    lam[2] = is2 ? lam2f[1] : lam1f[1];
    lam[3] = is2 ? lam2f[2] : 1.0f;
    lam[4] = is2 ? lam2f[3] : lam1f[2];
    lam[5] = is2 ? lam2f[4] : lam1f[3];
    lam[6] = is2 ? lam2f[5] : 1.0f;
    lam[7] = is2 ? lam2f[6] : lam1f[4];
    lam[8] = is2 ? lam2f[7] : lam1f[5];

    float dA = lam[0]*lam[0]*Rinv[0] + lam[1]*lam[1]*Rinv[1] + lam[2]*lam[2]*Rinv[2];
    float dB = lam[3]*lam[3]*Rinv[3] + lam[4]*lam[4]*Rinv[4] + lam[5]*lam[5]*Rinv[5];
    float dC = lam[6]*lam[6]*Rinv[6] + lam[7]*lam[7]*Rinv[7] + lam[8]*lam[8]*Rinv[8];
    float Dd0 = is2 ? (dA + dB + dC) : dA;
    float Dd1 = is2 ? 0.0f : dB;
    float Dd2 = is2 ? 0.0f : dC;

    float Q0 = fabsf(is2 ? q2d[0] : q1d[0]) + 1e-4f;
    float Q1 = fabsf(is2 ? q2d[1] : q1d[1]) + 1e-4f;
    float Q2 = fabsf(is2 ? q2d[2] : q1d[2]) + 1e-4f;

    float P0 = 1000.0f, P1s = 0.0f, P2s = 0.0f, P3 = 1000.0f, P4 = 0.0f, P5 = 1000.0f;

    #pragma unroll 1
    for (int t = 0; t < NTT; ++t) {
        float M00 = Bm[0]*P0  + Bm[1]*P1s + Bm[2]*P2s;
        float M01 = Bm[0]*P1s + Bm[1]*P3  + Bm[2]*P4;
        float M02 = Bm[0]*P2s + Bm[1]*P4  + Bm[2]*P5;
        float M10 = Bm[3]*P0  + Bm[4]*P1s + Bm[5]*P2s;
        float M11 = Bm[3]*P1s + Bm[4]*P3  + Bm[5]*P4;
        float M12 = Bm[3]*P2s + Bm[4]*P4  + Bm[5]*P5;
        float M20 = Bm[6]*P0  + Bm[7]*P1s + Bm[8]*P2s;
        float M21 = Bm[6]*P1s + Bm[7]*P3  + Bm[8]*P4;
        float M22 = Bm[6]*P2s + Bm[7]*P4  + Bm[8]*P5;

        float pp00 = M00*Bm[0] + M01*Bm[1] + M02*Bm[2] + Q0;
        float pp01 = M00*Bm[3] + M01*Bm[4] + M02*Bm[5];
        float pp02 = M00*Bm[6] + M01*Bm[7] + M02*Bm[8];
        float pp11 = M10*Bm[3] + M11*Bm[4] + M12*Bm[5] + Q1;
        float pp12 = M10*Bm[6] + M11*Bm[7] + M12*Bm[8];
        float pp22 = M20*Bm[6] + M21*Bm[7] + M22*Bm[8] + Q2;

        float c00 = pp11*pp22 - pp12*pp12;
        float c01 = pp02*pp12 - pp01*pp22;
        float c02 = pp01*pp12 - pp02*pp11;
        float c11 = pp00*pp22 - pp02*pp02;
        float c12 = pp01*pp02 - pp00*pp12;
        float c22 = pp00*pp11 - pp01*pp01;
        float detP = pp00*c00 + pp01*c01 + pp02*c02;
        float idet = 1.0f / detP;

        float s00 = c00*idet + Dd0;
        float s01 = c01*idet;
        float s02 = c02*idet;
        float s11 = c11*idet + Dd1;
        float s12 = c12*idet;
        float s22 = c22*idet + Dd2;

        float E00 = s11*s22 - s12*s12;
        float E01 = s02*s12 - s01*s22;
        float E02 = s01*s12 - s02*s11;
        float E11 = s00*s22 - s02*s02;
        float E12 = s01*s02 - s00*s12;
        float E22 = s00*s11 - s01*s01;
        float detS = s00*E00 + s01*E01 + s02*E02;
        float idetS = 1.0f / detS;

        float Sv0 = E00*idetS, Sv1 = E01*idetS, Sv2 = E02*idetS;
        float Sv3 = E11*idetS, Sv4 = E12*idetS, Sv5 = E22*idetS;
        float logc = -0.5f * (C0 + __logf(detP * detS));

        if (lane < 2) {
            float4* tv = (float4*)tab + (size_t)(t * 2 + lane) * 2;
            tv[0] = make_float4(Sv0, Sv1, Sv2, Sv3);
            tv[1] = make_float4(Sv4, Sv5, logc, 0.0f);
        }

        P0 = Sv0; P1s = Sv1; P2s = Sv2; P3 = Sv3; P4 = Sv4; P5 = Sv5;
    }
}

// ---------------------------------------------------------------------------
// Kernel 2: per-subject data-dependent recursion. Two lanes per subject
// (even = regime 1, odd = regime 2). Covariance table read from LDS.
// ---------------------------------------------------------------------------
__global__ __launch_bounds__(64, 1) void rskf_main(
    const float* __restrict__ y,
    const float* __restrict__ b1_r1, const float* __restrict__ lam1f,
    const float* __restrict__ b2_in, const float* __restrict__ lam2f,
    const float* __restrict__ r_in,
    const float* __restrict__ g1p, const float* __restrict__ g2p,
    const float* __restrict__ g3p, const float* __restrict__ g4p,
    const float* __restrict__ tab_g, float* __restrict__ out)
{
    __shared__ float tab[NTT * 2 * 8];   // 32 KB
    {
        const float4* src = (const float4*)tab_g;
        float4* dst = (float4*)tab;
        #pragma unroll 1
        for (int i = threadIdx.x; i < NTT * 2 * 2; i += 64) dst[i] = src[i];
    }
    __syncthreads();

    const int tid  = blockIdx.x * 64 + threadIdx.x;
    const int subj = tid >> 1;
    const int par  = tid & 1;
    const bool is2 = par != 0;

    float Rinv[9];
    #pragma unroll
    for (int i = 0; i < 9; ++i) Rinv[i] = 1.0f / (fabsf(r_in[i]) + 1e-4f);

    float Bm[9];
    {
        float a0 = b1_r1[0], a1 = b1_r1[1], a2 = b1_r1[2];
        Bm[0] = is2 ? b2_in[0] : a0;   Bm[1] = is2 ? b2_in[1] : 0.0f;
        Bm[2] = is2 ? b2_in[2] : 0.0f; Bm[3] = is2 ? b2_in[3] : 0.0f;
        Bm[4] = is2 ? b2_in[4] : a1;   Bm[5] = is2 ? b2_in[5] : 0.0f;
        Bm[6] = is2 ? b2_in[6] : 0.0f; Bm[7] = is2 ? b2_in[7] : 0.0f;
        Bm[8] = is2 ? b2_in[8] : a2;
    }
    float lam[9];
    lam[0] = 1.0f;
    lam[1] = is2 ? lam2f[0] : lam1f[0];
    lam[2] = is2 ? lam2f[1] : lam1f[1];
    lam[3] = is2 ? lam2f[2] : 1.0f;
    lam[4] = is2 ? lam2f[3] : lam1f[2];
    lam[5] = is2 ? lam2f[4] : lam1f[3];
    lam[6] = is2 ? lam2f[5] : 1.0f;
    lam[7] = is2 ? lam2f[6] : lam1f[4];
    lam[8] = is2 ? lam2f[7] : lam1f[5];

    const float gs = is2 ? g3p[0] : g1p[0];
    const float gv0 = is2 ? g4p[0] : g2p[0];
    const float gv1 = is2 ? g4p[1] : g2p[1];
    const float gv2 = is2 ? g4p[2] : g2p[2];

    float e0 = 0.0f, e1 = 0.0f, e2 = 0.0f;
    float mA = is2 ? 0.01f : 0.99f;
    float mB = is2 ? 0.99f : 0.01f;
    float llacc = 0.0f;

    const float* ybase = y + (size_t)subj * (NTT * OBS);
    float ya[9], yb[9];
    #pragma unroll
    for (int j = 0; j < 9; ++j) { ya[j] = ybase[j]; yb[j] = ybase[9 + j]; }

    // per-parity base into the LDS table: entry t at tvp[t*4], tvp[t*4+1]
    const float4* tvp = (const float4*)tab + par * 2;
    float4 taA0 = tvp[0 * 4], taA1 = tvp[0 * 4 + 1];
    float4 taB0 = tvp[1 * 4], taB1 = tvp[1 * 4 + 1];

    auto step = [&](float (&buf)[9], const float* ldy, bool doload,
                    float4& ta0, float4& ta1, int nt) {
        float S00 = ta0.x, S01 = ta0.y, S02 = ta0.z, S11 = ta0.w;
        float S12 = ta1.x, S22 = ta1.y, logc = ta1.z;
        // prefetch table entry for step nt (state-independent)
        ta0 = tvp[nt * 4];
        ta1 = tvp[nt * 4 + 1];

        // ---- mixture transition (pre-update eta) ----
        float d   = gs + e0*gv0 + e1*gv1 + e2*gv2;
        float sig = fast_rcp(1.0f + __expf(-d));
        float oth = swap1(sig);
        float mp  = sig * mA + (1.0f - oth) * mB;
        float lmp = __logf(mp + 1e-9f);

        // ---- state prediction ----
        float ep0 = Bm[0]*e0 + Bm[1]*e1 + Bm[2]*e2;
        float ep1 = Bm[3]*e0 + Bm[4]*e1 + Bm[5]*e2;
        float ep2 = Bm[6]*e0 + Bm[7]*e1 + Bm[8]*e2;
        float es1 = is2 ? ep0 : ep1;
        float es2 = is2 ? ep0 : ep2;

        float v0 = buf[0] - lam[0]*ep0;
        float v1 = buf[1] - lam[1]*ep0;
        float v2 = buf[2] - lam[2]*ep0;
        float v3 = buf[3] - lam[3]*es1;
        float v4 = buf[4] - lam[4]*es1;
        float v5 = buf[5] - lam[5]*es1;
        float v6 = buf[6] - lam[6]*es2;
        float v7 = buf[7] - lam[7]*es2;
        float v8 = buf[8] - lam[8]*es2;

        // buf consumed: prefetch y for step t+2
        if (doload) {
            #pragma unroll
            for (int j = 0; j < 9; ++j) buf[j] = ldy[j];
        } else {
            #pragma unroll
            for (int j = 0; j < 9; ++j) buf[j] = 0.0f;
        }

        float vr0 = v0*Rinv[0], vr1 = v1*Rinv[1], vr2 = v2*Rinv[2];
        float vr3 = v3*Rinv[3], vr4 = v4*Rinv[4], vr5 = v5*Rinv[5];
        float vr6 = v6*Rinv[6], vr7 = v7*Rinv[7], vr8 = v8*Rinv[8];
        float vRv = v0*vr0 + v1*vr1 + v2*vr2 + v3*vr3 + v4*vr4
                  + v5*vr5 + v6*vr6 + v7*vr7 + v8*vr8;

        float pA = lam[0]*vr0 + lam[1]*vr1 + lam[2]*vr2;
        float pB = lam[3]*vr3 + lam[4]*vr4 + lam[5]*vr5;
        float pC = lam[6]*vr6 + lam[7]*vr7 + lam[8]*vr8;
        float t0v = is2 ? (pA + pB + pC) : pA;
        float t1v = is2 ? 0.0f : pB;
        float t2v = is2 ? 0.0f : pC;

        // x = Sinv * t ; quad = t.x
        float x0 = S00*t0v + S01*t1v + S02*t2v;
        float x1 = S01*t0v + S11*t1v + S12*t2v;
        float x2 = S02*t0v + S12*t1v + S22*t2v;
        float quad = t0v*x0 + t1v*x1 + t2v*x2;

        float llo = logc - 0.5f*vRv + 0.5f*quad;

        e0 = ep0 + x0; e1 = ep1 + x1; e2 = ep2 + x2;

        // ---- mixture update: stable 2-way logsumexp, 1 exp + 1 log + 1 rcp ----
        float lj  = llo + lmp;
        float ljo = swap1(lj);
        float u   = ljo - lj;
        float et  = __expf(-fabsf(u));
        float r   = fast_rcp(1.0f + et);
        llacc += fmaxf(lj, ljo) + __logf(1.0f + et);
        mA = (u <= 0.0f) ? r : et * r;
        mB = 1.0f - mA;
    };

    const float* pl = ybase + 18;   // t+2 stream
    #pragma unroll 1
    for (int t = 0; t < NTT; t += 2) {
        int ntA = (t + 2 < NTT) ? t + 2 : NTT - 1;
        int ntB = (t + 3 < NTT) ? t + 3 : NTT - 1;
        step(ya, pl,     t + 2 < NTT, taA0, taA1, ntA);
        step(yb, pl + 9, t + 3 < NTT, taB0, taB1, ntB);
        pl += 18;
    }

    // ---- wave reduction; lane pair double-counts -> scale 0.5 ----
    float v = llacc;
    v += __shfl_down(v, 32);
    v += __shfl_down(v, 16);
    v += __shfl_down(v, 8);
    v += __shfl_down(v, 4);
    v += __shfl_down(v, 2);
    v += __shfl_down(v, 1);
    if (threadIdx.x == 0) atomicAdd(out, -0.5f * v);
}

extern "C" void kernel_launch(void* const* d_in, const int* in_sizes, int n_in,
                              void* d_out, int out_size, void* d_ws, size_t ws_size,
                              hipStream_t stream) {
    const float* y      = (const float*)d_in[0];
    const float* b1_r1  = (const float*)d_in[1];
    const float* lam1f  = (const float*)d_in[2];
    const float* q1d    = (const float*)d_in[3];
    const float* b2     = (const float*)d_in[4];
    const float* lam2f  = (const float*)d_in[5];
    const float* q2d    = (const float*)d_in[6];
    const float* r_in   = (const float*)d_in[7];
    const float* g1     = (const float*)d_in[8];
    const float* g2     = (const float*)d_in[9];
    const float* g3     = (const float*)d_in[10];
    const float* g4     = (const float*)d_in[11];
    float* out = (float*)d_out;
    float* tab = (float*)d_ws;          // 512*2*8 floats = 32 KB

    hipLaunchKernelGGL(zero_out_kernel, dim3(1), dim3(1), 0, stream, out);
    hipLaunchKernelGGL(precomp_kernel, dim3(1), dim3(64), 0, stream,
                       b1_r1, lam1f, q1d, b2, lam2f, q2d, r_in, tab);
    hipLaunchKernelGGL(rskf_main, dim3((NSUBJ * 2) / 64), dim3(64), 0, stream,
                       y, b1_r1, lam1f, b2, lam2f, r_in, g1, g2, g3, g4, tab, out);
}

// Round 4
// 325.953 us; speedup vs baseline: 1.6829x; 1.6829x over previous
//
#include <hip/hip_runtime.h>
#include <math.h>

#define NSUBJ 8192
#define NTT   512
#define OBS   9
#define LOG2PI 1.8378770664093453f

#define CHUNKS   8
#define REALSTEP 64          // real (ll-accumulating) steps per chunk
#define WARMSTEP 64          // warm-up steps for chunks > 0
#define SERIAL_P 96          // serial Riccati steps before steady-state fill

__global__ void zero_out_kernel(float* out) { out[0] = 0.0f; }

__device__ __forceinline__ float fast_rcp(float x) { return __builtin_amdgcn_rcpf(x); }

// Swap adjacent lanes (0<->1, 2<->3, ...) via DPP quad_perm [1,0,3,2].
__device__ __forceinline__ float swap1(float x) {
    int r = __builtin_amdgcn_update_dpp(0, __float_as_int(x), 0xB1, 0xF, 0xF, true);
    return __int_as_float(r);
}

// ---------------------------------------------------------------------------
// Kernel 1: data-independent Riccati recursion. Contractive -> run SERIAL_P
// steps, then fill the remaining table entries with the steady state.
// Lane parity = regime; every lane computes its parity's recursion (redundant
// across pairs, harmless), so after the loop each lane holds the steady state
// in registers for the cooperative fill.
// tab entry (t, regime): [Sinv(6), logc, pad] = 8 floats.
// ---------------------------------------------------------------------------
__global__ __launch_bounds__(64, 1) void precomp_kernel(
    const float* __restrict__ b1_r1, const float* __restrict__ lam1f,
    const float* __restrict__ q1d,   const float* __restrict__ b2_in,
    const float* __restrict__ lam2f, const float* __restrict__ q2d,
    const float* __restrict__ r_in,  float* __restrict__ tab)
{
    const int lane = threadIdx.x;
    const bool is2 = (lane & 1) != 0;

    float Rinv[9];
    float logdetR = 0.0f;
    #pragma unroll
    for (int i = 0; i < 9; ++i) {
        float r = fabsf(r_in[i]) + 1e-4f;
        Rinv[i] = fast_rcp(r);
        logdetR += __logf(r);
    }
    const float C0 = 9.0f * LOG2PI + logdetR;

    float Bm[9];
    {
        float a0 = b1_r1[0], a1 = b1_r1[1], a2 = b1_r1[2];
        Bm[0] = is2 ? b2_in[0] : a0;   Bm[1] = is2 ? b2_in[1] : 0.0f;
        Bm[2] = is2 ? b2_in[2] : 0.0f; Bm[3] = is2 ? b2_in[3] : 0.0f;
        Bm[4] = is2 ? b2_in[4] : a1;   Bm[5] = is2 ? b2_in[5] : 0.0f;
        Bm[6] = is2 ? b2_in[6] : 0.0f; Bm[7] = is2 ? b2_in[7] : 0.0f;
        Bm[8] = is2 ? b2_in[8] : a2;
    }
    float lam[9];
    lam[0] = 1.0f;
    lam[1] = is2 ? lam2f[0] : lam1f[0];
    lam[2] = is2 ? lam2f[1] : lam1f[1];
    lam[3] = is2 ? lam2f[2] : 1.0f;
    lam[4] = is2 ? lam2f[3] : lam1f[2];
    lam[5] = is2 ? lam2f[4] : lam1f[3];
    lam[6] = is2 ? lam2f[5] : 1.0f;
    lam[7] = is2 ? lam2f[6] : lam1f[4];
    lam[8] = is2 ? lam2f[7] : lam1f[5];

    float dA = lam[0]*lam[0]*Rinv[0] + lam[1]*lam[1]*Rinv[1] + lam[2]*lam[2]*Rinv[2];
    float dB = lam[3]*lam[3]*Rinv[3] + lam[4]*lam[4]*Rinv[4] + lam[5]*lam[5]*Rinv[5];
    float dC = lam[6]*lam[6]*Rinv[6] + lam[7]*lam[7]*Rinv[7] + lam[8]*lam[8]*Rinv[8];
    float Dd0 = is2 ? (dA + dB + dC) : dA;
    float Dd1 = is2 ? 0.0f : dB;
    float Dd2 = is2 ? 0.0f : dC;

    float Q0 = fabsf(is2 ? q2d[0] : q1d[0]) + 1e-4f;
    float Q1 = fabsf(is2 ? q2d[1] : q1d[1]) + 1e-4f;
    float Q2 = fabsf(is2 ? q2d[2] : q1d[2]) + 1e-4f;

    float P0 = 1000.0f, P1s = 0.0f, P2s = 0.0f, P3 = 1000.0f, P4 = 0.0f, P5 = 1000.0f;
    float Sv0, Sv1, Sv2, Sv3, Sv4, Sv5, logc;

    #pragma unroll 1
    for (int t = 0; t < SERIAL_P; ++t) {
        float M00 = Bm[0]*P0  + Bm[1]*P1s + Bm[2]*P2s;
        float M01 = Bm[0]*P1s + Bm[1]*P3  + Bm[2]*P4;
        float M02 = Bm[0]*P2s + Bm[1]*P4  + Bm[2]*P5;
        float M10 = Bm[3]*P0  + Bm[4]*P1s + Bm[5]*P2s;
        float M11 = Bm[3]*P1s + Bm[4]*P3  + Bm[5]*P4;
        float M12 = Bm[3]*P2s + Bm[4]*P4  + Bm[5]*P5;
        float M20 = Bm[6]*P0  + Bm[7]*P1s + Bm[8]*P2s;
        float M21 = Bm[6]*P1s + Bm[7]*P3  + Bm[8]*P4;
        float M22 = Bm[6]*P2s + Bm[7]*P4  + Bm[8]*P5;

        float pp00 = M00*Bm[0] + M01*Bm[1] + M02*Bm[2] + Q0;
        float pp01 = M00*Bm[3] + M01*Bm[4] + M02*Bm[5];
        float pp02 = M00*Bm[6] + M01*Bm[7] + M02*Bm[8];
        float pp11 = M10*Bm[3] + M11*Bm[4] + M12*Bm[5] + Q1;
        float pp12 = M10*Bm[6] + M11*Bm[7] + M12*Bm[8];
        float pp22 = M20*Bm[6] + M21*Bm[7] + M22*Bm[8] + Q2;

        float c00 = pp11*pp22 - pp12*pp12;
        float c01 = pp02*pp12 - pp01*pp22;
        float c02 = pp01*pp12 - pp02*pp11;
        float c11 = pp00*pp22 - pp02*pp02;
        float c12 = pp01*pp02 - pp00*pp12;
        float c22 = pp00*pp11 - pp01*pp01;
        float detP = pp00*c00 + pp01*c01 + pp02*c02;
        float idet = fast_rcp(detP);

        float s00 = c00*idet + Dd0;
        float s01 = c01*idet;
        float s02 = c02*idet;
        float s11 = c11*idet + Dd1;
        float s12 = c12*idet;
        float s22 = c22*idet + Dd2;

        float E00 = s11*s22 - s12*s12;
        float E01 = s02*s12 - s01*s22;
        float E02 = s01*s12 - s02*s11;
        float E11 = s00*s22 - s02*s02;
        float E12 = s01*s02 - s00*s12;
        float E22 = s00*s11 - s01*s01;
        float detS = s00*E00 + s01*E01 + s02*E02;
        float idetS = fast_rcp(detS);

        Sv0 = E00*idetS; Sv1 = E01*idetS; Sv2 = E02*idetS;
        Sv3 = E11*idetS; Sv4 = E12*idetS; Sv5 = E22*idetS;
        logc = -0.5f * (C0 + __logf(detP * detS));

        if (lane < 2) {
            float4* tv = (float4*)tab + (size_t)(t * 2 + lane) * 2;
            tv[0] = make_float4(Sv0, Sv1, Sv2, Sv3);
            tv[1] = make_float4(Sv4, Sv5, logc, 0.0f);
        }
        P0 = Sv0; P1s = Sv1; P2s = Sv2; P3 = Sv3; P4 = Sv4; P5 = Sv5;
    }

    // Cooperative steady-state fill: every lane holds its parity's steady
    // state; pair p = lane>>1 fills t = SERIAL_P + p, + 32, + 64, ...
    const int par = lane & 1;
    for (int t = SERIAL_P + (lane >> 1); t < NTT; t += 32) {
        float4* tv = (float4*)tab + (size_t)(t * 2 + par) * 2;
        tv[0] = make_float4(Sv0, Sv1, Sv2, Sv3);
        tv[1] = make_float4(Sv4, Sv5, logc, 0.0f);
    }
}

// ---------------------------------------------------------------------------
// Kernel 2: time-chunked per-subject recursion. Two lanes per subject
// (even = regime 1, odd = regime 2). 8 chunks of 64 real steps; chunks > 0
// prepend 64 warm-up steps (filter forgets init geometrically; no ll accum).
// ---------------------------------------------------------------------------
__global__ __launch_bounds__(64, 1) void rskf_main(
    const float* __restrict__ y,
    const float* __restrict__ b1_r1, const float* __restrict__ lam1f,
    const float* __restrict__ b2_in, const float* __restrict__ lam2f,
    const float* __restrict__ r_in,
    const float* __restrict__ g1p, const float* __restrict__ g2p,
    const float* __restrict__ g3p, const float* __restrict__ g4p,
    const float* __restrict__ tab_g, float* __restrict__ out)
{
    const int chunk = blockIdx.x & (CHUNKS - 1);
    const int sgrp  = blockIdx.x >> 3;
    const int subj  = sgrp * 32 + (threadIdx.x >> 1);
    const int par   = threadIdx.x & 1;
    const bool is2  = par != 0;

    const int t_real0 = chunk * REALSTEP;
    const int slice0  = (chunk == 0) ? 0 : t_real0 - WARMSTEP;
    const int nsteps  = (chunk == 0) ? REALSTEP : (WARMSTEP + REALSTEP);
    const int warmN   = nsteps - REALSTEP;

    // table slice [slice0, slice0+128) -> LDS (8 KB)
    __shared__ float tab[128 * 2 * 8];
    {
        const float4* src = (const float4*)tab_g + (size_t)slice0 * 4;
        float4* dst = (float4*)tab;
        #pragma unroll 1
        for (int i = threadIdx.x; i < 128 * 4; i += 64) dst[i] = src[i];
    }
    __syncthreads();

    float Rinv[9];
    #pragma unroll
    for (int i = 0; i < 9; ++i) Rinv[i] = 1.0f / (fabsf(r_in[i]) + 1e-4f);

    float Bm[9];
    {
        float a0 = b1_r1[0], a1 = b1_r1[1], a2 = b1_r1[2];
        Bm[0] = is2 ? b2_in[0] : a0;   Bm[1] = is2 ? b2_in[1] : 0.0f;
        Bm[2] = is2 ? b2_in[2] : 0.0f; Bm[3] = is2 ? b2_in[3] : 0.0f;
        Bm[4] = is2 ? b2_in[4] : a1;   Bm[5] = is2 ? b2_in[5] : 0.0f;
        Bm[6] = is2 ? b2_in[6] : 0.0f; Bm[7] = is2 ? b2_in[7] : 0.0f;
        Bm[8] = is2 ? b2_in[8] : a2;
    }
    float lam[9];
    lam[0] = 1.0f;
    lam[1] = is2 ? lam2f[0] : lam1f[0];
    lam[2] = is2 ? lam2f[1] : lam1f[1];
    lam[3] = is2 ? lam2f[2] : 1.0f;
    lam[4] = is2 ? lam2f[3] : lam1f[2];
    lam[5] = is2 ? lam2f[4] : lam1f[3];
    lam[6] = is2 ? lam2f[5] : 1.0f;
    lam[7] = is2 ? lam2f[6] : lam1f[4];
    lam[8] = is2 ? lam2f[7] : lam1f[5];

    const float gs  = is2 ? g3p[0] : g1p[0];
    const float gv0 = is2 ? g4p[0] : g2p[0];
    const float gv1 = is2 ? g4p[1] : g2p[1];
    const float gv2 = is2 ? g4p[2] : g2p[2];

    float e0 = 0.0f, e1 = 0.0f, e2 = 0.0f;
    float mA = (chunk == 0) ? (is2 ? 0.01f : 0.99f) : 0.5f;
    float mB = 1.0f - mA;
    float llacc = 0.0f;

    const float* ybase = y + (size_t)subj * (NTT * OBS) + (size_t)slice0 * OBS;
    float ya[9], yb[9];
    #pragma unroll
    for (int j = 0; j < 9; ++j) { ya[j] = ybase[j]; yb[j] = ybase[9 + j]; }

    const float4* tvp = (const float4*)tab + par * 2;
    float4 taA0 = tvp[0], taA1 = tvp[1];
    float4 taB0 = tvp[4], taB1 = tvp[5];

    auto step = [&](float (&buf)[9], const float* ldy, bool doload,
                    float4& ta0, float4& ta1, int nt, bool real) {
        float S00 = ta0.x, S01 = ta0.y, S02 = ta0.z, S11 = ta0.w;
        float S12 = ta1.x, S22 = ta1.y, logc = ta1.z;
        ta0 = tvp[nt * 4];
        ta1 = tvp[nt * 4 + 1];

        float d   = gs + e0*gv0 + e1*gv1 + e2*gv2;
        float sig = fast_rcp(1.0f + __expf(-d));
        float oth = swap1(sig);
        float mp  = sig * mA + (1.0f - oth) * mB;
        float lmp = __logf(mp + 1e-9f);

        float ep0 = Bm[0]*e0 + Bm[1]*e1 + Bm[2]*e2;
        float ep1 = Bm[3]*e0 + Bm[4]*e1 + Bm[5]*e2;
        float ep2 = Bm[6]*e0 + Bm[7]*e1 + Bm[8]*e2;
        float es1 = is2 ? ep0 : ep1;
        float es2 = is2 ? ep0 : ep2;

        float v0 = buf[0] - lam[0]*ep0;
        float v1 = buf[1] - lam[1]*ep0;
        float v2 = buf[2] - lam[2]*ep0;
        float v3 = buf[3] - lam[3]*es1;
        float v4 = buf[4] - lam[4]*es1;
        float v5 = buf[5] - lam[5]*es1;
        float v6 = buf[6] - lam[6]*es2;
        float v7 = buf[7] - lam[7]*es2;
        float v8 = buf[8] - lam[8]*es2;

        if (doload) {
            #pragma unroll
            for (int j = 0; j < 9; ++j) buf[j] = ldy[j];
        } else {
            #pragma unroll
            for (int j = 0; j < 9; ++j) buf[j] = 0.0f;
        }

        float vr0 = v0*Rinv[0], vr1 = v1*Rinv[1], vr2 = v2*Rinv[2];
        float vr3 = v3*Rinv[3], vr4 = v4*Rinv[4], vr5 = v5*Rinv[5];
        float vr6 = v6*Rinv[6], vr7 = v7*Rinv[7], vr8 = v8*Rinv[8];
        float vRv = v0*vr0 + v1*vr1 + v2*vr2 + v3*vr3 + v4*vr4
                  + v5*vr5 + v6*vr6 + v7*vr7 + v8*vr8;

        float pA = lam[0]*vr0 + lam[1]*vr1 + lam[2]*vr2;
        float pB = lam[3]*vr3 + lam[4]*vr4 + lam[5]*vr5;
        float pC = lam[6]*vr6 + lam[7]*vr7 + lam[8]*vr8;
        float t0v = is2 ? (pA + pB + pC) : pA;
        float t1v = is2 ? 0.0f : pB;
        float t2v = is2 ? 0.0f : pC;

        float x0 = S00*t0v + S01*t1v + S02*t2v;
        float x1 = S01*t0v + S11*t1v + S12*t2v;
        float x2 = S02*t0v + S12*t1v + S22*t2v;
        float quad = t0v*x0 + t1v*x1 + t2v*x2;

        float llo = logc - 0.5f*vRv + 0.5f*quad;

        e0 = ep0 + x0; e1 = ep1 + x1; e2 = ep2 + x2;

        float lj  = llo + lmp;
        float ljo = swap1(lj);
        float u   = ljo - lj;
        float et  = __expf(-fabsf(u));
        float r   = fast_rcp(1.0f + et);
        float lm  = fmaxf(lj, ljo) + __logf(1.0f + et);
        if (real) llacc += lm;
        mA = (u <= 0.0f) ? r : et * r;
        mB = 1.0f - mA;
    };

    const float* pl = ybase + 18;
    #pragma unroll 1
    for (int i = 0; i < nsteps; i += 2) {
        int ntA = (i + 2 < nsteps) ? i + 2 : nsteps - 1;
        int ntB = (i + 3 < nsteps) ? i + 3 : nsteps - 1;
        step(ya, pl,     i + 2 < nsteps, taA0, taA1, ntA, i     >= warmN);
        step(yb, pl + 9, i + 3 < nsteps, taB0, taB1, ntB, i + 1 >= warmN);
        pl += 18;
    }

    // wave reduction; lane pair double-counts -> 0.5
    float v = llacc;
    v += __shfl_down(v, 32);
    v += __shfl_down(v, 16);
    v += __shfl_down(v, 8);
    v += __shfl_down(v, 4);
    v += __shfl_down(v, 2);
    v += __shfl_down(v, 1);
    if (threadIdx.x == 0) atomicAdd(out, -0.5f * v);
}

extern "C" void kernel_launch(void* const* d_in, const int* in_sizes, int n_in,
                              void* d_out, int out_size, void* d_ws, size_t ws_size,
                              hipStream_t stream) {
    const float* y      = (const float*)d_in[0];
    const float* b1_r1  = (const float*)d_in[1];
    const float* lam1f  = (const float*)d_in[2];
    const float* q1d    = (const float*)d_in[3];
    const float* b2     = (const float*)d_in[4];
    const float* lam2f  = (const float*)d_in[5];
    const float* q2d    = (const float*)d_in[6];
    const float* r_in   = (const float*)d_in[7];
    const float* g1     = (const float*)d_in[8];
    const float* g2     = (const float*)d_in[9];
    const float* g3     = (const float*)d_in[10];
    const float* g4     = (const float*)d_in[11];
    float* out = (float*)d_out;
    float* tab = (float*)d_ws;          // 512*2*8 floats = 32 KB

    hipLaunchKernelGGL(zero_out_kernel, dim3(1), dim3(1), 0, stream, out);
    hipLaunchKernelGGL(precomp_kernel, dim3(1), dim3(64), 0, stream,
                       b1_r1, lam1f, q1d, b2, lam2f, q2d, r_in, tab);
    hipLaunchKernelGGL(rskf_main, dim3((NSUBJ / 32) * CHUNKS), dim3(64), 0, stream,
                       y, b1_r1, lam1f, b2, lam2f, r_in, g1, g2, g3, g4, tab, out);
}